// Round 1
// baseline (1126.942 us; speedup 1.0000x reference)
//
#include <hip/hip_runtime.h>
#include <hip/hip_bf16.h>
#include <math.h>

#define N_NODES 40000
#define NE      640000
#define FIN     33
#define H       128
#define COUT    3
#define NLAYERS 8
#define ALPHA   0.1f
#define THETA   0.5f

// ---------------- CSR build ----------------
__global__ void k_hist(const int* __restrict__ row, int* __restrict__ counts) {
    int e = blockIdx.x * blockDim.x + threadIdx.x;
    if (e < NE) atomicAdd(&counts[row[e]], 1);
}

// single block, 256 threads: exclusive scan of counts -> row_ptr, cursor
__global__ void k_scan(const int* __restrict__ counts, int* __restrict__ row_ptr,
                       int* __restrict__ cursor) {
    __shared__ int sums[256];
    const int T = 256;
    const int chunk = (N_NODES + T - 1) / T;   // 157
    int t = threadIdx.x;
    int begin = t * chunk;
    int end = begin + chunk; if (end > N_NODES) end = N_NODES;
    int s = 0;
    for (int i = begin; i < end; i++) s += counts[i];
    sums[t] = s;
    __syncthreads();
    // Hillis-Steele inclusive scan over 256 partials
    for (int off = 1; off < T; off <<= 1) {
        int v = sums[t];
        int add = (t >= off) ? sums[t - off] : 0;
        __syncthreads();
        sums[t] = v + add;
        __syncthreads();
    }
    int run = (t == 0) ? 0 : sums[t - 1];
    for (int i = begin; i < end; i++) {
        row_ptr[i] = run; cursor[i] = run;
        run += counts[i];
    }
    if (t == T - 1) row_ptr[N_NODES] = run;   // == NE
}

__global__ void k_scatter(const int* __restrict__ row, const int* __restrict__ col,
                          const float* __restrict__ w, int* __restrict__ cursor,
                          int* __restrict__ scol, float* __restrict__ sw) {
    int e = blockIdx.x * blockDim.x + threadIdx.x;
    if (e < NE) {
        int r = row[e];
        int pos = atomicAdd(&cursor[r], 1);
        scol[pos] = col[e];
        sw[pos] = (1.0f - ALPHA) * w[e];   // fold (1-alpha) into edge weight
    }
}

// ---------------- x0 = relu(x @ W_in^T + b_in); h = x0 ----------------
__global__ __launch_bounds__(256) void k_xin(const float* __restrict__ x,
                      const float* __restrict__ Win, const float* __restrict__ bin,
                      float* __restrict__ x0, float* __restrict__ h) {
    __shared__ float sW[H * FIN];      // 128*33*4 = 16.9 KB
    __shared__ float sx[2][FIN];
    int t = threadIdx.x;
    for (int i = t; i < H * FIN; i += 256) sW[i] = Win[i];
    int n0 = blockIdx.x * 2;
    for (int i = t; i < 2 * FIN; i += 256) {
        int nn = n0 + i / FIN;
        sx[i / FIN][i % FIN] = (nn < N_NODES) ? x[(size_t)nn * FIN + (i % FIN)] : 0.f;
    }
    __syncthreads();
    int local = t / H;            // 0..1
    int f = t % H;
    int n = n0 + local;
    if (n < N_NODES) {
        float acc = bin[f];
        #pragma unroll
        for (int k = 0; k < FIN; k++) acc += sx[local][k] * sW[f * FIN + k];
        acc = fmaxf(acc, 0.f);
        x0[(size_t)n * H + f] = acc;
        h [(size_t)n * H + f] = acc;
    }
}

// ---------------- xx = (1-a)*A@h + a*x0  (wave per row) ----------------
__global__ __launch_bounds__(256) void k_spmm(const int* __restrict__ row_ptr,
                       const int* __restrict__ scol, const float* __restrict__ sw,
                       const float* __restrict__ hin, const float* __restrict__ x0,
                       float* __restrict__ xx) {
    int wave = (blockIdx.x * blockDim.x + threadIdx.x) >> 6;
    int lane = threadIdx.x & 63;
    if (wave >= N_NODES) return;
    int beg = row_ptr[wave], end = row_ptr[wave + 1];
    float2 acc = {0.f, 0.f};
    for (int e = beg; e < end; e++) {
        int c = scol[e];
        float w = sw[e];              // already scaled by (1-alpha)
        float2 v = ((const float2*)(hin + (size_t)c * H))[lane];
        acc.x += w * v.x; acc.y += w * v.y;
    }
    float2 xv = ((const float2*)(x0 + (size_t)wave * H))[lane];
    float2 o;
    o.x = acc.x + ALPHA * xv.x;
    o.y = acc.y + ALPHA * xv.y;
    ((float2*)(xx + (size_t)wave * H))[lane] = o;
}

// ---------------- h += relu((1-b)*xx + b*(xx @ W)) ----------------
// block: 256 threads, tile = 32 rows x 128 cols; thread = 4 rows x 4 cols
__global__ __launch_bounds__(256) void k_gemm(const float* __restrict__ xx,
                       const float* __restrict__ W, float* __restrict__ h,
                       float beta) {
    __shared__ float sW[64][H];        // 32 KB (K-chunk of W)
    __shared__ float sX[32][H + 1];    // 16.5 KB, padded
    int t = threadIdx.x;
    int row0 = blockIdx.x * 32;
    for (int i = t; i < 32 * H; i += 256) {
        int r = i / H, k = i % H;
        sX[r][k] = xx[(size_t)(row0 + r) * H + k];
    }
    int tx = t % 32;
    int ty = t / 32;                   // 0..7
    float acc[4][4] = {};
    for (int kk = 0; kk < H; kk += 64) {
        __syncthreads();
        for (int i = t; i < 64 * H; i += 256)
            sW[i / H][i % H] = W[(size_t)(kk + i / H) * H + (i % H)];
        __syncthreads();
        for (int k = 0; k < 64; k++) {
            float b0 = sW[k][tx], b1 = sW[k][tx + 32], b2 = sW[k][tx + 64], b3 = sW[k][tx + 96];
            #pragma unroll
            for (int r = 0; r < 4; r++) {
                float a = sX[ty * 4 + r][kk + k];
                acc[r][0] += a * b0; acc[r][1] += a * b1;
                acc[r][2] += a * b2; acc[r][3] += a * b3;
            }
        }
    }
    float omb = 1.f - beta;
    #pragma unroll
    for (int r = 0; r < 4; r++) {
        int n = row0 + ty * 4 + r;
        #pragma unroll
        for (int c = 0; c < 4; c++) {
            int col = tx + 32 * c;
            float xv = sX[ty * 4 + r][col];
            float o = omb * xv + beta * acc[r][c];
            h[(size_t)n * H + col] += fmaxf(o, 0.f);
        }
    }
}

// ---------------- out = h @ W_out^T + b_out  (wave per node) ----------------
__global__ __launch_bounds__(256) void k_out(const float* __restrict__ h,
                      const float* __restrict__ Wout, const float* __restrict__ bout,
                      float* __restrict__ out) {
    int wave = (blockIdx.x * blockDim.x + threadIdx.x) >> 6;
    int lane = threadIdx.x & 63;
    if (wave >= N_NODES) return;
    float2 v = ((const float2*)(h + (size_t)wave * H))[lane];
    float p0, p1, p2;
    {
        float2 w0 = ((const float2*)(Wout + 0 * H))[lane];
        float2 w1 = ((const float2*)(Wout + 1 * H))[lane];
        float2 w2 = ((const float2*)(Wout + 2 * H))[lane];
        p0 = v.x * w0.x + v.y * w0.y;
        p1 = v.x * w1.x + v.y * w1.y;
        p2 = v.x * w2.x + v.y * w2.y;
    }
    #pragma unroll
    for (int off = 32; off > 0; off >>= 1) {
        p0 += __shfl_down(p0, off);
        p1 += __shfl_down(p1, off);
        p2 += __shfl_down(p2, off);
    }
    if (lane == 0) {
        out[(size_t)wave * 3 + 0] = p0 + bout[0];
        out[(size_t)wave * 3 + 1] = p1 + bout[1];
        out[(size_t)wave * 3 + 2] = p2 + bout[2];
    }
}

extern "C" void kernel_launch(void* const* d_in, const int* in_sizes, int n_in,
                              void* d_out, int out_size, void* d_ws, size_t ws_size,
                              hipStream_t stream) {
    const float* x     = (const float*)d_in[0];
    const int*   erow  = (const int*)  d_in[1];
    const int*   ecol  = (const int*)  d_in[2];
    const float* ew    = (const float*)d_in[3];
    const float* Win   = (const float*)d_in[4];
    const float* bin   = (const float*)d_in[5];
    const float* Wout  = (const float*)d_in[6];
    const float* bout  = (const float*)d_in[7];
    const float* Wconv = (const float*)d_in[8];
    float* out = (float*)d_out;

    char* ws = (char*)d_ws;
    const size_t NH = (size_t)N_NODES * H * sizeof(float);   // 20,480,000 B
    float* x0      = (float*)(ws);
    float* h       = (float*)(ws + NH);
    float* xx      = (float*)(ws + 2 * NH);
    char*  p       = ws + 3 * NH;
    int*   counts  = (int*)  p;  p += 160256;   // N ints, padded
    int*   row_ptr = (int*)  p;  p += 160256;   // N+1 ints, padded
    int*   cursor  = (int*)  p;  p += 160256;   // N ints, padded
    int*   scol    = (int*)  p;  p += (size_t)NE * 4;
    float* sw      = (float*)p;

    // CSR build (every call; inputs re-restored each launch)
    hipMemsetAsync(counts, 0, (size_t)N_NODES * 4, stream);
    k_hist   <<<NE / 256, 256, 0, stream>>>(erow, counts);
    k_scan   <<<1,        256, 0, stream>>>(counts, row_ptr, cursor);
    k_scatter<<<NE / 256, 256, 0, stream>>>(erow, ecol, ew, cursor, scol, sw);

    // input projection
    k_xin<<<N_NODES / 2, 256, 0, stream>>>(x, Win, bin, x0, h);

    // layers
    for (int l = 0; l < NLAYERS; l++) {
        float beta = logf(THETA / (float)(l + 1) + 1.0f);
        k_spmm<<<N_NODES / 4, 256, 0, stream>>>(row_ptr, scol, sw, h, x0, xx);
        k_gemm<<<N_NODES / 32, 256, 0, stream>>>(xx, Wconv + (size_t)l * H * H, h, beta);
    }

    // output projection
    k_out<<<N_NODES / 4, 256, 0, stream>>>(h, Wout, bout, out);
}